// Round 4
// baseline (448.806 us; speedup 1.0000x reference)
//
#include <hip/hip_runtime.h>
#include <math.h>

#define NT 128        // trees
#define NB 1024       // batch
#define ND 784        // feature dim
#define NK 200        // top-k
#define ND4 196       // ND / 4
#define TND4 (NT * ND4)        // 25088 vfloat4 per batch row
#define TOTAL4 (NB * TND4)     // 25,690,112 vfloat4 total
#define GTHREADS (1024 * 256)  // grid threads
#define ITERS (TOTAL4 / GTHREADS)   // 98 exactly

typedef float vfloat4 __attribute__((ext_vector_type(4)));

// ---------------------------------------------------------------------------
// Kernel 1 (unchanged): per-tree top-K, register-resident radix select.
// ---------------------------------------------------------------------------
__global__ __launch_bounds__(256) void topk_attention_kernel(
    const float* __restrict__ mask, float* __restrict__ att_out)
{
    __shared__ int wsum[32][4];
    __shared__ int wtie[4][4];

    const int t    = blockIdx.x;
    const int tid  = threadIdx.x;
    const int wave = tid >> 6;
    const int lane = tid & 63;

    unsigned int key[4];
    float        val[4];
    #pragma unroll
    for (int j = 0; j < 4; ++j) {
        const int d = tid + j * 256;
        if (d < ND) {
            const float f = mask[t * ND + d];
            const unsigned int b = __float_as_uint(f);
            key[j] = ((int)b < 0) ? ~b : (b | 0x80000000u);  // order-preserving
            val[j] = 1.0f / (1.0f + expf(-f));
        } else { key[j] = 0u; val[j] = 0.0f; }               // pad: never selected
    }

    unsigned int p = 0;
    int need = NK;
    for (int bit = 31; bit >= 0; --bit) {
        const unsigned int test = (p >> bit) | 1u;
        int c = 0;
        #pragma unroll
        for (int j = 0; j < 4; ++j) c += ((key[j] >> bit) == test) ? 1 : 0;
        #pragma unroll
        for (int off = 32; off > 0; off >>= 1) c += __shfl_down(c, off);
        if (lane == 0) wsum[bit][wave] = c;
        __syncthreads();
        const int tot = wsum[bit][0] + wsum[bit][1] + wsum[bit][2] + wsum[bit][3];
        if (tot >= need) p |= (1u << bit);
        else             need -= tot;
    }

    // ordered tie ranks: ascending d == ascending (j, wave, lane)
    int rankw[4];
    #pragma unroll
    for (int j = 0; j < 4; ++j) {
        const bool tie = (key[j] == p);
        const unsigned long long m = __ballot(tie);
        rankw[j] = __popcll(m & ((1ull << lane) - 1ull));
        if (lane == 0) wtie[j][wave] = __popcll(m);
    }
    __syncthreads();
    int jbase[4];
    {
        int pre = 0;
        #pragma unroll
        for (int j = 0; j < 4; ++j) {
            jbase[j] = pre;
            pre += wtie[j][0] + wtie[j][1] + wtie[j][2] + wtie[j][3];
        }
    }

    #pragma unroll
    for (int j = 0; j < 4; ++j) {
        const int d = tid + j * 256;
        if (d < ND) {
            bool keep = key[j] > p;
            if (key[j] == p) {
                int off = jbase[j] + rankw[j];
                for (int w = 0; w < 4; ++w) if (w < wave) off += wtie[j][w];
                keep = off < need;
            }
            att_out[t * ND + d] = keep ? val[j] : 0.0f;
        }
    }
}

// ---------------------------------------------------------------------------
// Kernel 2 v7: grid-stride, fill-shaped write ORDER. Single changed variable
// vs all prior variants: at any instant the whole GPU's stores land inside
// one contiguous ~4 MB moving slab (like the 6.3 TB/s rocclr fill), instead
// of 256..4096 private sequential streams scattered across the 411 MB output.
// Loads (att 401 KB, x 3 MB: both L2-resident; proven free in R1) are
// prefetched one iteration ahead via rolling registers — issued BEFORE the
// current store so the in-order vmcnt queue never couples store retirement
// to load consumption. Index math is magic-mul VALU, hidden under store BW.
// ---------------------------------------------------------------------------
__global__ __launch_bounds__(256) void bcast_mul_kernel(
    const vfloat4* __restrict__ x4, const vfloat4* __restrict__ att4,
    vfloat4* __restrict__ out4)
{
    unsigned n = blockIdx.x * 256u + threadIdx.x;   // linear vfloat4 index

    // prologue: loads for iteration 0
    unsigned b  = n / (unsigned)TND4;
    unsigned r  = n - b * (unsigned)TND4;
    unsigned d4 = r % (unsigned)ND4;
    vfloat4 a  = att4[r];
    vfloat4 xs = x4[b * (unsigned)ND4 + d4];

    #pragma unroll 2
    for (int it = 0; it < ITERS - 1; ++it) {
        const unsigned n2  = n + (unsigned)GTHREADS;
        const unsigned b2  = n2 / (unsigned)TND4;
        const unsigned r2  = n2 - b2 * (unsigned)TND4;
        const unsigned d42 = r2 % (unsigned)ND4;
        const vfloat4 a2  = att4[r2];                 // issue next loads first
        const vfloat4 x2  = x4[b2 * (unsigned)ND4 + d42];
        __builtin_nontemporal_store(a * xs, &out4[n]);
        n = n2; a = a2; xs = x2;
    }
    __builtin_nontemporal_store(a * xs, &out4[n]);
}

extern "C" void kernel_launch(void* const* d_in, const int* in_sizes, int n_in,
                              void* d_out, int out_size, void* d_ws, size_t ws_size,
                              hipStream_t stream)
{
    (void)in_sizes; (void)n_in; (void)out_size; (void)d_ws; (void)ws_size;
    const float* x    = (const float*)d_in[0];
    const float* mask = (const float*)d_in[1];
    float* out = (float*)d_out;
    float* att = out + (size_t)NB * NT * ND;   // attention output region

    topk_attention_kernel<<<NT, 256, 0, stream>>>(mask, att);
    bcast_mul_kernel<<<GTHREADS / 256, 256, 0, stream>>>(
        (const vfloat4*)x, (const vfloat4*)att, (vfloat4*)out);
}

// Round 5
// 421.602 us; speedup vs baseline: 1.0645x; 1.0645x over previous
//
#include <hip/hip_runtime.h>
#include <math.h>

#define NT 128        // trees
#define NB 1024       // batch
#define ND 784        // feature dim
#define NK 200        // top-k
#define ND4 196       // ND / 4
#define UB 7          // bcast pipeline batch (98 iters = 14 batches of 7)

typedef float vfloat4 __attribute__((ext_vector_type(4)));

// ---------------------------------------------------------------------------
// Kernel 1: per-tree top-K, register-resident radix select.
// Block per tree, 256 threads; each thread owns 4 keys in VGPRs (no LDS reads
// in the 32-bit loop). One barrier per bit via [32][4] slot array. Tie-pick
// (lowest index first, matches lax.top_k) via ballot+popcount ordered rank.
// sigmoid monotonic => top-k(sigmoid(m)) == top-k(m).
// ---------------------------------------------------------------------------
__global__ __launch_bounds__(256) void topk_attention_kernel(
    const float* __restrict__ mask, float* __restrict__ att_out)
{
    __shared__ int wsum[32][4];
    __shared__ int wtie[4][4];

    const int t    = blockIdx.x;
    const int tid  = threadIdx.x;
    const int wave = tid >> 6;
    const int lane = tid & 63;

    unsigned int key[4];
    float        val[4];
    #pragma unroll
    for (int j = 0; j < 4; ++j) {
        const int d = tid + j * 256;
        if (d < ND) {
            const float f = mask[t * ND + d];
            const unsigned int b = __float_as_uint(f);
            key[j] = ((int)b < 0) ? ~b : (b | 0x80000000u);  // order-preserving
            val[j] = 1.0f / (1.0f + expf(-f));
        } else { key[j] = 0u; val[j] = 0.0f; }               // pad: never selected
    }

    unsigned int p = 0;
    int need = NK;
    for (int bit = 31; bit >= 0; --bit) {
        const unsigned int test = (p >> bit) | 1u;
        int c = 0;
        #pragma unroll
        for (int j = 0; j < 4; ++j) c += ((key[j] >> bit) == test) ? 1 : 0;
        #pragma unroll
        for (int off = 32; off > 0; off >>= 1) c += __shfl_down(c, off);
        if (lane == 0) wsum[bit][wave] = c;
        __syncthreads();
        const int tot = wsum[bit][0] + wsum[bit][1] + wsum[bit][2] + wsum[bit][3];
        if (tot >= need) p |= (1u << bit);
        else             need -= tot;
    }

    // ordered tie ranks: ascending d == ascending (j, wave, lane)
    int rankw[4];
    #pragma unroll
    for (int j = 0; j < 4; ++j) {
        const bool tie = (key[j] == p);
        const unsigned long long m = __ballot(tie);
        rankw[j] = __popcll(m & ((1ull << lane) - 1ull));
        if (lane == 0) wtie[j][wave] = __popcll(m);
    }
    __syncthreads();
    int jbase[4];
    {
        int pre = 0;
        #pragma unroll
        for (int j = 0; j < 4; ++j) {
            jbase[j] = pre;
            pre += wtie[j][0] + wtie[j][1] + wtie[j][2] + wtie[j][3];
        }
    }

    #pragma unroll
    for (int j = 0; j < 4; ++j) {
        const int d = tid + j * 256;
        if (d < ND) {
            bool keep = key[j] > p;
            if (key[j] == p) {
                int off = jbase[j] + rankw[j];
                for (int w = 0; w < 4; ++w) if (w < wave) off += wtie[j][w];
                keep = off < need;
            }
            att_out[t * ND + d] = keep ? val[j] : 0.0f;
        }
    }
}

// ---------------------------------------------------------------------------
// Kernel 2 (v3, best measured: 421.4 µs total; reproduced at 422.1 by the
// sc0/sc1/nt variant). Block per batch row b; x row in LDS; att prefetched
// in register batches of UB=7 with loads issued BEFORE the previous batch's
// stores, so the load-consume s_waitcnt never drains outstanding nt stores
// (loads+stores share one in-order vmcnt queue on CDNA).
//
// Experiment matrix (all null or negative — do not revisit):
//   att-read traffic /4 (RR=4):        424.6
//   fill-shaped 50k tiny blocks:       436.1
//   sc0 sc1 nt store policy:           422.1
//   grid-stride compact write slab:    448.8
// Residual gap to pure-write roofline is harness-fixed (260 µs poison fill
// in the timed region + its ~256 MB Infinity-Cache drain overlapping us).
// ---------------------------------------------------------------------------
__global__ __launch_bounds__(256) void bcast_mul_kernel(
    const vfloat4* __restrict__ x4, const vfloat4* __restrict__ att4,
    vfloat4* __restrict__ out4)
{
    __shared__ vfloat4 sx[ND4];
    const int b   = blockIdx.x;
    const int tid = threadIdx.x;
    if (tid < ND4) sx[tid] = x4[b * ND4 + tid];
    __syncthreads();

    vfloat4* __restrict__ outb = out4 + (size_t)b * (NT * ND4);

    vfloat4 cur[UB];
    #pragma unroll
    for (int u = 0; u < UB; ++u) cur[u] = att4[tid + u * 256];

    int d4 = (tid >= ND4) ? tid - ND4 : tid;   // (tid + 256k) mod 196, k=0

    for (int nb = 0; nb < 13; ++nb) {          // batches 0..12 prefetch next
        vfloat4 nxt[UB];
        const int kb = nb * UB;
        #pragma unroll
        for (int u = 0; u < UB; ++u) nxt[u] = att4[tid + (kb + UB + u) * 256];
        #pragma unroll
        for (int u = 0; u < UB; ++u) {
            const vfloat4 o = cur[u] * sx[d4];
            __builtin_nontemporal_store(o, &outb[tid + (kb + u) * 256]);
            d4 += 60; if (d4 >= ND4) d4 -= ND4;   // (i+256) mod 196
        }
        #pragma unroll
        for (int u = 0; u < UB; ++u) cur[u] = nxt[u];
    }
    // final batch (13): stores only
    #pragma unroll
    for (int u = 0; u < UB; ++u) {
        const vfloat4 o = cur[u] * sx[d4];
        __builtin_nontemporal_store(o, &outb[tid + (13 * UB + u) * 256]);
        d4 += 60; if (d4 >= ND4) d4 -= ND4;
    }
}

extern "C" void kernel_launch(void* const* d_in, const int* in_sizes, int n_in,
                              void* d_out, int out_size, void* d_ws, size_t ws_size,
                              hipStream_t stream)
{
    (void)in_sizes; (void)n_in; (void)out_size; (void)d_ws; (void)ws_size;
    const float* x    = (const float*)d_in[0];
    const float* mask = (const float*)d_in[1];
    float* out = (float*)d_out;
    float* att = out + (size_t)NB * NT * ND;   // attention output region

    topk_attention_kernel<<<NT, 256, 0, stream>>>(mask, att);
    bcast_mul_kernel<<<NB, 256, 0, stream>>>(
        (const vfloat4*)x, (const vfloat4*)att, (vfloat4*)out);
}